// Round 4
// baseline (733.824 us; speedup 1.0000x reference)
//
#include <hip/hip_runtime.h>

typedef unsigned short u16;
typedef unsigned int u32;
typedef __attribute__((ext_vector_type(8))) short short8;
typedef __attribute__((ext_vector_type(4))) float f32x4;

#define DIMC 768
#define NQKV 2304
#define NPOS 32768
#define NKT 12   // 768 / 64

__device__ __forceinline__ float b2f(u16 u) {
    union { u32 i; float f; } c; c.i = ((u32)u) << 16; return c.f;
}
__device__ __forceinline__ u16 f2b(float f) {
    union { float f; u32 i; } c; c.f = f;
    u32 r = c.i + 0x7fffu + ((c.i >> 16) & 1u);
    return (u16)(r >> 16);
}

// async global->LDS, 16B per lane; lds dst is wave-uniform base + lane*16
__device__ __forceinline__ void gl_lds16(const void* g, void* l) {
    __builtin_amdgcn_global_load_lds(
        (const __attribute__((address_space(1))) void*)g,
        (__attribute__((address_space(3))) void*)l, 16, 0, 0);
}

// ---- fp32 -> bf16 elementwise (x) ----
__global__ __launch_bounds__(256) void cvt_bf16(
    const float* __restrict__ in, u16* __restrict__ out, int n4)
{
    int i = blockIdx.x * 256 + threadIdx.x;
    if (i >= n4) return;
    float4 v = ((const float4*)in)[i];
    ushort4 o;
    o.x = f2b(v.x); o.y = f2b(v.y); o.z = f2b(v.z); o.w = f2b(v.w);
    ((ushort4*)out)[i] = o;
}

// ---- fp32 W[768][N] -> bf16 WT[N][768] (transpose + convert), 64x64 tiles ----
__global__ __launch_bounds__(256) void cvt_wT(
    const float* __restrict__ W0, const float* __restrict__ W1,
    const float* __restrict__ W2,
    u16* __restrict__ T0, u16* __restrict__ T1, u16* __restrict__ T2)
{
    const int z = blockIdx.z;
    const float* W = (z == 0) ? W0 : (z == 1) ? W1 : W2;
    u16* WT = (z == 0) ? T0 : (z == 1) ? T1 : T2;
    const int N = (z == 2) ? 768 : 2304;
    const int nb = blockIdx.x, kb = blockIdx.y;
    if (nb * 64 >= N) return;                       // block-uniform
    __shared__ u16 T[64][65];
    const int t = threadIdx.x, sr = t >> 2, sc = t & 3;
    {
        const float4* p = (const float4*)(W + (size_t)(kb * 64 + sr) * N + nb * 64 + sc * 16);
        float4 a0 = p[0], a1 = p[1], a2 = p[2], a3 = p[3];
        float vv[16] = {a0.x, a0.y, a0.z, a0.w, a1.x, a1.y, a1.z, a1.w,
                        a2.x, a2.y, a2.z, a2.w, a3.x, a3.y, a3.z, a3.w};
        #pragma unroll
        for (int i = 0; i < 16; ++i)
            T[sc * 16 + i][sr] = f2b(vv[i]);
    }
    __syncthreads();
    {
        u16 vv[16];
        #pragma unroll
        for (int i = 0; i < 16; ++i) vv[i] = T[sr][sc * 16 + i];
        uint4 p0, p1;
        p0.x = vv[0] | ((u32)vv[1] << 16);  p0.y = vv[2] | ((u32)vv[3] << 16);
        p0.z = vv[4] | ((u32)vv[5] << 16);  p0.w = vv[6] | ((u32)vv[7] << 16);
        p1.x = vv[8] | ((u32)vv[9] << 16);  p1.y = vv[10] | ((u32)vv[11] << 16);
        p1.z = vv[12] | ((u32)vv[13] << 16); p1.w = vv[14] | ((u32)vv[15] << 16);
        u16* q = WT + (size_t)(nb * 64 + sr) * DIMC + kb * 64 + sc * 16;
        *(uint4*)q = p0;
        *(uint4*)(q + 8) = p1;
    }
}

// ============================================================================
// 256x256 MFMA GEMM, 4 phases / 4 barriers per K-tile, with ONE-PHASE-AHEAD
// register prefetch: every MFMA's ds_reads were issued >=1 full phase earlier.
// 512 threads = 8 waves (2M x 4N); per-wave output 128x64; BK=64.
// LDS 128 KiB: 2 dbuf x ([256][64] A + [256][64] B), XOR-swizzled (T2).
//
// Register schedule (tile T, buf p): af_a=A0(T), af_b=A1(T), b0=B0(T), b1=B1(T)
//   pre-P1 (in prev tile P4, post-BAR): read af_a, b0
//   P1: stage B1(T+1)->q; read b1;      BAR; MM(0,0)(af_a,b0)
//   P2: stage A1(T+1)->q; read af_b;    BAR; MM(0,1)(af_a,b1)
//   P3: stage A0(T+2)->p;               BAR; MM(1,0)(af_b,b0)
//   P4: stage B0(T+2)->p; vmcnt(4); BAR; read af_a'=A0(T+1),b0'=B0(T+1);
//       MM(1,1)(af_b,b1)
// vmcnt(4) at P4 completes exactly tile T+1's 4 halves (issued 3-5 phases
// earlier: A0/B0 at T-1 P3/P4, B1/A1 at T P1/P2), leaves T+2's 2 stages in
// flight. Stage-issue vs prior-reads-of-region separated by >=1 barrier after
// the reads were lgkm-consumed (verified per region) -> cross-wave sound.
// ============================================================================

#define STAGE_A(buf, kt, ht) do {                                              \
    gl_lds16(aS + (size_t)((ht) * 128)      * DIMC + (size_t)(kt) * 64,        \
             &As[buf][(ht) * 8192 +        w * 512]);                          \
    gl_lds16(aS + (size_t)((ht) * 128 + 64) * DIMC + (size_t)(kt) * 64,        \
             &As[buf][(ht) * 8192 + 4096 + w * 512]);                          \
} while (0)

#define STAGE_B(buf, kt, ht) do {                                              \
    gl_lds16(bS + (size_t)((ht) * 128)      * DIMC + (size_t)(kt) * 64,        \
             &Bs[buf][(ht) * 8192 +        w * 512]);                          \
    gl_lds16(bS + (size_t)((ht) * 128 + 64) * DIMC + (size_t)(kt) * 64,        \
             &Bs[buf][(ht) * 8192 + 4096 + w * 512]);                          \
} while (0)

// read A half hm (rows hm*128 + wm*64 + i*16 + lr) into dst
#define READ_A(dst, base, hm) do {                                             \
    _Pragma("unroll")                                                          \
    for (int i_ = 0; i_ < 4; ++i_) {                                           \
        const int row_ = (hm) * 128 + wm * 64 + i_ * 16 + lr;                  \
        _Pragma("unroll")                                                      \
        for (int ks_ = 0; ks_ < 2; ++ks_)                                      \
            (dst)[i_][ks_] = *(const short8*)((base) + (row_ << 6) +           \
                              (((ks_ * 4 + lq) ^ (row_ & 7)) << 3));           \
    }                                                                          \
} while (0)

// read B half hn (rows hn*128 + wn*32 + j*16 + lr) into dst
#define READ_B(dst, base, hn) do {                                             \
    _Pragma("unroll")                                                          \
    for (int j_ = 0; j_ < 2; ++j_) {                                           \
        const int row_ = (hn) * 128 + wn * 32 + j_ * 16 + lr;                  \
        _Pragma("unroll")                                                      \
        for (int ks_ = 0; ks_ < 2; ++ks_)                                      \
            (dst)[j_][ks_] = *(const short8*)((base) + (row_ << 6) +           \
                              (((ks_ * 4 + lq) ^ (row_ & 7)) << 3));           \
    }                                                                          \
} while (0)

#define MM(hm, hn, asrc, bsrc) do {                                            \
    __builtin_amdgcn_s_setprio(1);                                             \
    _Pragma("unroll")                                                          \
    for (int i_ = 0; i_ < 4; ++i_)                                             \
        _Pragma("unroll")                                                      \
        for (int j_ = 0; j_ < 2; ++j_)                                         \
            _Pragma("unroll")                                                  \
            for (int ks_ = 0; ks_ < 2; ++ks_)                                  \
                acc[(hm) * 4 + i_][(hn) * 2 + j_] =                            \
                    __builtin_amdgcn_mfma_f32_16x16x32_bf16(                   \
                        (asrc)[i_][ks_], (bsrc)[j_][ks_],                      \
                        acc[(hm) * 4 + i_][(hn) * 2 + j_], 0, 0, 0);           \
    __builtin_amdgcn_s_setprio(0);                                             \
} while (0)

#define BAR() do {                                                             \
    __builtin_amdgcn_sched_barrier(0);                                         \
    __builtin_amdgcn_s_barrier();                                              \
    __builtin_amdgcn_sched_barrier(0);                                         \
} while (0)

// One K-tile. S12: stage kt+1 B1/A1. S34: stage kt+2 A0/B0.
// SNEXT: prefetch next tile's af_a/b0 at P4. VN: vmcnt arg at P4.
#define KTILE(kt, S12, S34, SNEXT, VN) do {                                    \
    const int p_ = (kt) & 1, q_ = p_ ^ 1;                                      \
    /* ---- P1 ---- */                                                         \
    if (S12) STAGE_B(q_, (kt) + 1, 1);                                         \
    READ_B(b1, Bs[p_], 1);                                                     \
    BAR();                                                                     \
    MM(0, 0, af_a, b0);                                                        \
    /* ---- P2 ---- */                                                         \
    if (S12) STAGE_A(q_, (kt) + 1, 1);                                         \
    READ_A(af_b, As[p_], 1);                                                   \
    BAR();                                                                     \
    MM(0, 1, af_a, b1);                                                        \
    /* ---- P3 ---- */                                                         \
    if (S34) STAGE_A(p_, (kt) + 2, 0);                                         \
    BAR();                                                                     \
    MM(1, 0, af_b, b0);                                                        \
    /* ---- P4 ---- */                                                         \
    if (S34) STAGE_B(p_, (kt) + 2, 0);                                         \
    __builtin_amdgcn_sched_barrier(0);                                         \
    asm volatile("s_waitcnt vmcnt(" VN ")" ::: "memory");                      \
    BAR();                                                                     \
    if (SNEXT) { READ_A(af_a, As[q_], 0); READ_B(b0, Bs[q_], 0); }             \
    MM(1, 1, af_b, b1);                                                        \
} while (0)

__global__ __launch_bounds__(512, 2) void gemm256(
    const u16* __restrict__ A, const u16* __restrict__ BT,
    const float* __restrict__ bias, void* __restrict__ C,
    int ldn, int c_is_f32)
{
    __shared__ __align__(16) u16 As[2][256 * 64];   // 64 KiB
    __shared__ __align__(16) u16 Bs[2][256 * 64];   // 64 KiB

    const int t = threadIdx.x;
    const int w = t >> 6, l = t & 63;
    const int wm = w >> 2, wn = w & 3;              // 2M x 4N wave grid
    const int lr = l & 15, lq = l >> 4;

    // T1: bijective XCD swizzle (nwg = 1152 or 384, both % 8 == 0)
    const int gx = (int)gridDim.x;
    const int nwg = gx * (int)gridDim.y;
    const int lin = (int)blockIdx.y * gx + (int)blockIdx.x;
    const int swz = (lin & 7) * (nwg >> 3) + (lin >> 3);
    const int by = swz / gx, bx = swz - by * gx;
    const int mBase = by * 256, nBase = bx * 256;

    // staging source (pre-swizzled so linear global_load_lds yields
    // LDS[row][c] = global chunk c^(row&7))
    const int srow = t >> 3;                         // 0..63
    const int schk = (t & 7) ^ (srow & 7);           // swizzled 16B chunk
    const u16* aS = A  + (size_t)(mBase + srow) * DIMC + schk * 8;
    const u16* bS = BT + (size_t)(nBase + srow) * DIMC + schk * 8;

    f32x4 acc[8][4];
    #pragma unroll
    for (int i = 0; i < 8; ++i)
        #pragma unroll
        for (int j = 0; j < 4; ++j)
            acc[i][j] = (f32x4){0.f, 0.f, 0.f, 0.f};

    short8 af_a[4][2], af_b[4][2], b0[2][2], b1[2][2];

    // prologue: tile0 all 4 halves (buf0) + tile1 A0,B0 (buf1).
    // vmcnt(4) waits tile0's 8 instrs, leaves tile1's 4 in flight.
    STAGE_A(0, 0, 0); STAGE_B(0, 0, 0); STAGE_B(0, 0, 1); STAGE_A(0, 0, 1);
    STAGE_A(1, 1, 0); STAGE_B(1, 1, 0);
    __builtin_amdgcn_sched_barrier(0);
    asm volatile("s_waitcnt vmcnt(4)" ::: "memory");
    BAR();
    READ_A(af_a, As[0], 0);
    READ_B(b0, Bs[0], 0);

    #pragma unroll 1
    for (int kt = 0; kt < NKT - 2; ++kt) { KTILE(kt, 1, 1, 1, "4"); }
    { KTILE(NKT - 2, 1, 0, 1, "0"); }
    { KTILE(NKT - 1, 0, 0, 0, "0"); }

    // epilogue: C/D layout col=lane&15, row=(lane>>4)*4+reg (m89-verified)
    #pragma unroll
    for (int hn = 0; hn < 2; ++hn)
        #pragma unroll
        for (int j = 0; j < 2; ++j) {
            const int col = nBase + hn * 128 + wn * 32 + j * 16 + lr;
            const float bb = bias[col];
            #pragma unroll
            for (int hm = 0; hm < 2; ++hm)
                #pragma unroll
                for (int i = 0; i < 4; ++i) {
                    const int row = mBase + hm * 128 + wm * 64 + i * 16 + lq * 4;
                    #pragma unroll
                    for (int rg = 0; rg < 4; ++rg) {
                        float v = acc[hm * 4 + i][hn * 2 + j][rg] + bb;
                        size_t idx = (size_t)(row + rg) * ldn + col;
                        if (c_is_f32) ((float*)C)[idx] = v;
                        else          ((u16*)C)[idx]   = f2b(v);
                    }
                }
        }
}

// ============================================================================
// Fused dual head-attention: one wave per position, 4 waves/block.
// Reads BOTH qkv rows (h- and w-branch), computes both 12x12 head-attentions,
// writes sum row once (no accumulate round-trip).
// QK^T via 2x mfma_16x16x32 with frags loaded DIRECT from global
//   (lane: row=l&15, k=(l>>4)*8; rows 12..15 garbage, masked in softmax).
// Softmax: wave-parallel shfl_xor reduce within 16-lane groups.
// PV via VALU: P stays in registers, broadcast by __shfl; V staged row-major
// in per-wave LDS (conflict-free b128 writes, 2-lane/bank u16 reads).
// Output: 12 contiguous 128B row-stores per wave (fully coalesced).
// ============================================================================
__device__ __forceinline__ void attn_one(
    short8 qa0, short8 qa1, short8 kb0, short8 kb1,
    const u16* __restrict__ V, float* o, int lr, int l)
{
    f32x4 s = (f32x4){0.f, 0.f, 0.f, 0.f};
    s = __builtin_amdgcn_mfma_f32_16x16x32_bf16(qa0, kb0, s, 0, 0, 0);
    s = __builtin_amdgcn_mfma_f32_16x16x32_bf16(qa1, kb1, s, 0, 0, 0);
    float pp[4];
    #pragma unroll
    for (int rg = 0; rg < 4; ++rg) {
        float x = (lr < 12) ? s[rg] * 0.125f : -1e30f;
        float m = x;
        m = fmaxf(m, __shfl_xor(m, 1));
        m = fmaxf(m, __shfl_xor(m, 2));
        m = fmaxf(m, __shfl_xor(m, 4));
        m = fmaxf(m, __shfl_xor(m, 8));
        float e = (lr < 12) ? __expf(x - m) : 0.f;
        float ss = e;
        ss += __shfl_xor(ss, 1);
        ss += __shfl_xor(ss, 2);
        ss += __shfl_xor(ss, 4);
        ss += __shfl_xor(ss, 8);
        pp[rg] = e / ss;
    }
    #pragma unroll
    for (int g = 0; g < 12; ++g) {
        float vg = b2f(V[g * 64 + l]);
        #pragma unroll
        for (int h = 0; h < 12; ++h)
            o[h] = fmaf(__shfl(pp[h & 3], (h >> 2) * 16 + g), vg, o[h]);
    }
}

__global__ __launch_bounds__(256) void headattn2(
    const u16* __restrict__ qkv1, const u16* __restrict__ qkv2,
    u16* __restrict__ sum)
{
    __shared__ __align__(16) u16 VL[4][2][768];   // per-wave V rows [12][64]
    const int t = threadIdx.x, wv = t >> 6, l = t & 63;
    const int p = blockIdx.x * 4 + wv;
    const u16* r1 = qkv1 + (size_t)p * NQKV;
    const u16* r2 = qkv2 + (size_t)p * NQKV;
    const int lr = l & 15;
    const int fo = lr * 64 + (l >> 4) * 8;          // frag offset

    // ---- issue all global loads up front ----
    short8 qa0_1 = *(const short8*)(r1 + fo);
    short8 qa1_1 = *(const short8*)(r1 + fo + 32);
    short8 kb0_1 = *(const short8*)(r1 + 768 + fo);
    short8 kb1_1 = *(const short8*)(r1 + 768 + fo + 32);
    short8 qa0_2 = *(const short8*)(r2 + fo);
    short8 qa1_2 = *(const short8*)(r2 + fo + 32);
    short8 kb0_2 = *(const short8*)(r2 + 768 + fo);
    short8 kb1_2 = *(const short8*)(r2 + 768 + fo + 32);
    // V: 96 x 16B chunks per row; lane l -> chunk l (+ chunk 64+l if l<32)
    short8 v1a = *(const short8*)(r1 + 1536 + l * 8);
    short8 v2a = *(const short8*)(r2 + 1536 + l * 8);
    short8 v1b, v2b;
    if (l < 32) {
        v1b = *(const short8*)(r1 + 1536 + 512 + l * 8);
        v2b = *(const short8*)(r2 + 1536 + 512 + l * 8);
    }
    *(short8*)(&VL[wv][0][l * 8]) = v1a;
    *(short8*)(&VL[wv][1][l * 8]) = v2a;
    if (l < 32) {
        *(short8*)(&VL[wv][0][512 + l * 8]) = v1b;
        *(short8*)(&VL[wv][1][512 + l * 8]) = v2b;
    }

    float o[12];
    #pragma unroll
    for (int h = 0; h < 12; ++h) o[h] = 0.f;

    attn_one(qa0_1, qa1_1, kb0_1, kb1_1, VL[wv][0], o, lr, l);
    attn_one(qa0_2, qa1_2, kb0_2, kb1_2, VL[wv][1], o, lr, l);

    u16* orow = sum + (size_t)p * DIMC;
    #pragma unroll
    for (int h = 0; h < 12; ++h)
        orow[h * 64 + l] = f2b(o[h]);
}

extern "C" void kernel_launch(void* const* d_in, const int* in_sizes, int n_in,
                              void* d_out, int out_size, void* d_ws, size_t ws_size,
                              hipStream_t stream) {
    const float* x  = (const float*)d_in[0];
    const float* wh = (const float*)d_in[1];
    const float* bh = (const float*)d_in[2];
    const float* ww = (const float*)d_in[3];
    const float* bw = (const float*)d_in[4];
    const float* wp = (const float*)d_in[5];
    const float* bp = (const float*)d_in[6];
    float* out = (float*)d_out;

    // ws (u16 elems): xb 25165824 (reused as sumb after gemm2) | whT 1769472 |
    //   wwT 1769472 | wpT 589824 | qkv1 75497472 | qkv2 75497472  => ~361 MB
    u16* xb   = (u16*)d_ws;
    u16* sumb = xb;                      // aliases xb (dead after 2nd GEMM)
    u16* whT  = xb   + 25165824;
    u16* wwT  = whT  + 1769472;
    u16* wpT  = wwT  + 1769472;
    u16* qkv1 = wpT  + 589824;
    u16* qkv2 = qkv1 + 75497472;

    cvt_bf16<<<24576, 256, 0, stream>>>(x, xb, 6291456);
    dim3 wg(36, 12, 3);
    cvt_wT<<<wg, 256, 0, stream>>>(wh, ww, wp, whT, wwT, wpT);

    dim3 gq(NQKV / 256, NPOS / 256);      // (9, 128)  -> 1152 blocks
    dim3 gp(DIMC / 256, NPOS / 256);      // (3, 128)  ->  384 blocks

    gemm256<<<gq, 512, 0, stream>>>(xb, whT, bh, qkv1, NQKV, 0);
    gemm256<<<gq, 512, 0, stream>>>(xb, wwT, bw, qkv2, NQKV, 0);
    headattn2<<<NPOS / 4, 256, 0, stream>>>(qkv1, qkv2, sumb);
    gemm256<<<gp, 512, 0, stream>>>(sumb, wpT, bp, out, DIMC, 1);
}

// Round 5
// 617.759 us; speedup vs baseline: 1.1879x; 1.1879x over previous
//
#include <hip/hip_runtime.h>

typedef unsigned short u16;
typedef unsigned int u32;
typedef __attribute__((ext_vector_type(8))) short short8;
typedef __attribute__((ext_vector_type(4))) float f32x4;

#define DIMC 768
#define NQKV 2304
#define NPOS 32768
#define NKT 12   // 768 / 64

__device__ __forceinline__ float b2f(u16 u) {
    union { u32 i; float f; } c; c.i = ((u32)u) << 16; return c.f;
}
__device__ __forceinline__ u16 f2b(float f) {
    union { float f; u32 i; } c; c.f = f;
    u32 r = c.i + 0x7fffu + ((c.i >> 16) & 1u);
    return (u16)(r >> 16);
}

// async global->LDS, 16B per lane; lds dst is wave-uniform base + lane*16
__device__ __forceinline__ void gl_lds16(const void* g, void* l) {
    __builtin_amdgcn_global_load_lds(
        (const __attribute__((address_space(1))) void*)g,
        (__attribute__((address_space(3))) void*)l, 16, 0, 0);
}

// ---- fp32 -> bf16 elementwise (x) ----
__global__ __launch_bounds__(256) void cvt_bf16(
    const float* __restrict__ in, u16* __restrict__ out, int n4)
{
    int i = blockIdx.x * 256 + threadIdx.x;
    if (i >= n4) return;
    float4 v = ((const float4*)in)[i];
    ushort4 o;
    o.x = f2b(v.x); o.y = f2b(v.y); o.z = f2b(v.z); o.w = f2b(v.w);
    ((ushort4*)out)[i] = o;
}

// ---- fp32 W[768][N] -> bf16 WT[N][768] (transpose + convert), 64x64 tiles ----
__global__ __launch_bounds__(256) void cvt_wT(
    const float* __restrict__ W0, const float* __restrict__ W1,
    const float* __restrict__ W2,
    u16* __restrict__ T0, u16* __restrict__ T1, u16* __restrict__ T2)
{
    const int z = blockIdx.z;
    const float* W = (z == 0) ? W0 : (z == 1) ? W1 : W2;
    u16* WT = (z == 0) ? T0 : (z == 1) ? T1 : T2;
    const int N = (z == 2) ? 768 : 2304;
    const int nb = blockIdx.x, kb = blockIdx.y;
    if (nb * 64 >= N) return;                       // block-uniform
    __shared__ u16 T[64][65];
    const int t = threadIdx.x, sr = t >> 2, sc = t & 3;
    {
        const float4* p = (const float4*)(W + (size_t)(kb * 64 + sr) * N + nb * 64 + sc * 16);
        float4 a0 = p[0], a1 = p[1], a2 = p[2], a3 = p[3];
        float vv[16] = {a0.x, a0.y, a0.z, a0.w, a1.x, a1.y, a1.z, a1.w,
                        a2.x, a2.y, a2.z, a2.w, a3.x, a3.y, a3.z, a3.w};
        #pragma unroll
        for (int i = 0; i < 16; ++i)
            T[sc * 16 + i][sr] = f2b(vv[i]);
    }
    __syncthreads();
    {
        u16 vv[16];
        #pragma unroll
        for (int i = 0; i < 16; ++i) vv[i] = T[sr][sc * 16 + i];
        uint4 p0, p1;
        p0.x = vv[0] | ((u32)vv[1] << 16);  p0.y = vv[2] | ((u32)vv[3] << 16);
        p0.z = vv[4] | ((u32)vv[5] << 16);  p0.w = vv[6] | ((u32)vv[7] << 16);
        p1.x = vv[8] | ((u32)vv[9] << 16);  p1.y = vv[10] | ((u32)vv[11] << 16);
        p1.z = vv[12] | ((u32)vv[13] << 16); p1.w = vv[14] | ((u32)vv[15] << 16);
        u16* q = WT + (size_t)(nb * 64 + sr) * DIMC + kb * 64 + sc * 16;
        *(uint4*)q = p0;
        *(uint4*)(q + 8) = p1;
    }
}

// ============================================================================
// 256x256 MFMA GEMM, 4 phases / 4 barriers per K-tile (round-3 schedule —
// measured best: 146.5 us, MfmaUtil 34%, 0 bank conflicts; the r4 cross-phase
// register prefetch variant REGRESSED to 183 us and was reverted).
// 512 threads = 8 waves (2M x 4N); per-wave output 128x64; BK=64.
// LDS 128 KiB: 2 dbuf x ([256][64] A + [256][64] B), XOR-swizzled (T2).
//
// Stage slots (tile T): P1: B1(T+1)->q  P2: A1(T+1)->q  P3: A0(T+2)->p
//                       P4: B0(T+2)->p
// Reads (tile T from p): P1: af0(8)+b0(4); P2: b1(4); P3: af1(8); P4: none.
// Quadrants: P1 MM(0,0)  P2 MM(0,1)  P3 MM(1,0)  P4 MM(1,1).
// Single counted vmcnt(4) at P4 waits exactly tile T+1's four halves
// (issued 2..5 phases earlier), leaves T+2's A0,B0 in flight. Every vmcnt
// precedes a barrier -> cross-wave sound; every stage's target region was
// last read >=2 barriers earlier (reads consumed before that barrier).
// ============================================================================

#define STAGE_A(buf, kt, ht) do {                                              \
    gl_lds16(aS + (size_t)((ht) * 128)      * DIMC + (size_t)(kt) * 64,        \
             &As[buf][(ht) * 8192 +        w * 512]);                          \
    gl_lds16(aS + (size_t)((ht) * 128 + 64) * DIMC + (size_t)(kt) * 64,        \
             &As[buf][(ht) * 8192 + 4096 + w * 512]);                          \
} while (0)

#define STAGE_B(buf, kt, ht) do {                                              \
    gl_lds16(bS + (size_t)((ht) * 128)      * DIMC + (size_t)(kt) * 64,        \
             &Bs[buf][(ht) * 8192 +        w * 512]);                          \
    gl_lds16(bS + (size_t)((ht) * 128 + 64) * DIMC + (size_t)(kt) * 64,        \
             &Bs[buf][(ht) * 8192 + 4096 + w * 512]);                          \
} while (0)

// read A half hm (rows hm*128 + wm*64 + i*16 + lr) into af
#define READ_A(base, hm) do {                                                  \
    _Pragma("unroll")                                                          \
    for (int i_ = 0; i_ < 4; ++i_) {                                           \
        const int row_ = (hm) * 128 + wm * 64 + i_ * 16 + lr;                  \
        _Pragma("unroll")                                                      \
        for (int ks_ = 0; ks_ < 2; ++ks_)                                      \
            af[i_][ks_] = *(const short8*)((base) + (row_ << 6) +              \
                              (((ks_ * 4 + lq) ^ (row_ & 7)) << 3));           \
    }                                                                          \
} while (0)

// read B half hn (rows hn*128 + wn*32 + j*16 + lr) into dst
#define READ_B(dst, base, hn) do {                                             \
    _Pragma("unroll")                                                          \
    for (int j_ = 0; j_ < 2; ++j_) {                                           \
        const int row_ = (hn) * 128 + wn * 32 + j_ * 16 + lr;                  \
        _Pragma("unroll")                                                      \
        for (int ks_ = 0; ks_ < 2; ++ks_)                                      \
            (dst)[j_][ks_] = *(const short8*)((base) + (row_ << 6) +           \
                              (((ks_ * 4 + lq) ^ (row_ & 7)) << 3));           \
    }                                                                          \
} while (0)

#define MM(hm, hn, bsrc) do {                                                  \
    __builtin_amdgcn_s_setprio(1);                                             \
    _Pragma("unroll")                                                          \
    for (int i_ = 0; i_ < 4; ++i_)                                             \
        _Pragma("unroll")                                                      \
        for (int j_ = 0; j_ < 2; ++j_)                                         \
            _Pragma("unroll")                                                  \
            for (int ks_ = 0; ks_ < 2; ++ks_)                                  \
                acc[(hm) * 4 + i_][(hn) * 2 + j_] =                            \
                    __builtin_amdgcn_mfma_f32_16x16x32_bf16(                   \
                        af[i_][ks_], (bsrc)[j_][ks_],                          \
                        acc[(hm) * 4 + i_][(hn) * 2 + j_], 0, 0, 0);           \
    __builtin_amdgcn_s_setprio(0);                                             \
} while (0)

#define BAR() do {                                                             \
    __builtin_amdgcn_sched_barrier(0);                                         \
    __builtin_amdgcn_s_barrier();                                              \
    __builtin_amdgcn_sched_barrier(0);                                         \
} while (0)

// One K-tile. S12: stage tile kt+1 halves B1/A1. S34: stage tile kt+2 A0/B0.
#define KTILE(kt, S12, S34, VN) do {                                           \
    const int p_ = (kt) & 1, q_ = p_ ^ 1;                                      \
    const u16* Ab_ = As[p_];                                                   \
    const u16* Bb_ = Bs[p_];                                                   \
    /* ---- P1 ---- */                                                         \
    READ_A(Ab_, 0);                                                            \
    READ_B(b0, Bb_, 0);                                                        \
    if (S12) STAGE_B(q_, (kt) + 1, 1);                                         \
    BAR();                                                                     \
    MM(0, 0, b0);                                                              \
    /* ---- P2 ---- */                                                         \
    READ_B(b1, Bb_, 1);                                                        \
    if (S12) STAGE_A(q_, (kt) + 1, 1);                                         \
    BAR();                                                                     \
    MM(0, 1, b1);                                                              \
    /* ---- P3 ---- */                                                         \
    READ_A(Ab_, 1);                                                            \
    if (S34) STAGE_A(p_, (kt) + 2, 0);                                         \
    BAR();                                                                     \
    MM(1, 0, b0);                                                              \
    /* ---- P4 ---- */                                                         \
    if (S34) STAGE_B(p_, (kt) + 2, 0);                                         \
    __builtin_amdgcn_sched_barrier(0);                                         \
    asm volatile("s_waitcnt vmcnt(" VN ")" ::: "memory");                      \
    BAR();                                                                     \
    MM(1, 1, b1);                                                              \
} while (0)

__global__ __launch_bounds__(512, 2) void gemm256(
    const u16* __restrict__ A, const u16* __restrict__ BT,
    const float* __restrict__ bias, void* __restrict__ C,
    int ldn, int c_is_f32)
{
    __shared__ __align__(16) u16 As[2][256 * 64];   // 64 KiB
    __shared__ __align__(16) u16 Bs[2][256 * 64];   // 64 KiB

    const int t = threadIdx.x;
    const int w = t >> 6, l = t & 63;
    const int wm = w >> 2, wn = w & 3;              // 2M x 4N wave grid
    const int lr = l & 15, lq = l >> 4;

    // T1: bijective XCD swizzle (nwg = 1152 or 384, both % 8 == 0)
    const int gx = (int)gridDim.x;
    const int nwg = gx * (int)gridDim.y;
    const int lin = (int)blockIdx.y * gx + (int)blockIdx.x;
    const int swz = (lin & 7) * (nwg >> 3) + (lin >> 3);
    const int by = swz / gx, bx = swz - by * gx;
    const int mBase = by * 256, nBase = bx * 256;

    // staging source (pre-swizzled so linear global_load_lds yields
    // LDS[row][c] = global chunk c^(row&7))
    const int srow = t >> 3;                         // 0..63
    const int schk = (t & 7) ^ (srow & 7);           // swizzled 16B chunk
    const u16* aS = A  + (size_t)(mBase + srow) * DIMC + schk * 8;
    const u16* bS = BT + (size_t)(nBase + srow) * DIMC + schk * 8;

    f32x4 acc[8][4];
    #pragma unroll
    for (int i = 0; i < 8; ++i)
        #pragma unroll
        for (int j = 0; j < 4; ++j)
            acc[i][j] = (f32x4){0.f, 0.f, 0.f, 0.f};

    short8 af[4][2], b0[2][2], b1[2][2];

    // prologue: tile0 all 4 halves (buf0) + tile1 A0,B0 (buf1).
    // vmcnt(4) waits tile0's 8 instrs, leaves tile1's 4 in flight.
    STAGE_A(0, 0, 0); STAGE_B(0, 0, 0); STAGE_B(0, 0, 1); STAGE_A(0, 0, 1);
    STAGE_A(1, 1, 0); STAGE_B(1, 1, 0);
    __builtin_amdgcn_sched_barrier(0);
    asm volatile("s_waitcnt vmcnt(4)" ::: "memory");
    BAR();

    #pragma unroll 1
    for (int kt = 0; kt < NKT - 2; ++kt) { KTILE(kt, 1, 1, "4"); }
    { KTILE(NKT - 2, 1, 0, "0"); }
    { KTILE(NKT - 1, 0, 0, "0"); }

    // epilogue: C/D layout col=lane&15, row=(lane>>4)*4+reg (m89-verified)
    #pragma unroll
    for (int hn = 0; hn < 2; ++hn)
        #pragma unroll
        for (int j = 0; j < 2; ++j) {
            const int col = nBase + hn * 128 + wn * 32 + j * 16 + lr;
            const float bb = bias[col];
            #pragma unroll
            for (int hm = 0; hm < 2; ++hm)
                #pragma unroll
                for (int i = 0; i < 4; ++i) {
                    const int row = mBase + hm * 128 + wm * 64 + i * 16 + lq * 4;
                    #pragma unroll
                    for (int rg = 0; rg < 4; ++rg) {
                        float v = acc[hm * 4 + i][hn * 2 + j][rg] + bb;
                        size_t idx = (size_t)(row + rg) * ldn + col;
                        if (c_is_f32) ((float*)C)[idx] = v;
                        else          ((u16*)C)[idx]   = f2b(v);
                    }
                }
        }
}

// ============================================================================
// Fused dual head-attention, ZERO LDS / zero barriers. One wave per position.
// QK^T via 2x mfma_16x16x32, frags direct from global (lane: row=l&15,
// k=(l>>4)*8; rows 12..15 read garbage, masked in softmax).
// Softmax: shfl_xor reduce within 16-lane groups (32 ds_swizzle/branch).
// PV: P[h][g] is wave-uniform -> v_readlane to SGPR (constant lane index
// after unroll) + v_fmac with SGPR operand. 144 readlane + 144 fma per
// branch, pure VALU — replaces r4's 288 ds_bpermute/branch (the r4 killer).
// V columns direct from global: V[g][l] is a 128B coalesced row-load per g.
// Output: 12 x 128B coalesced u16 row-stores, written once (fused sum).
// ============================================================================
__device__ __forceinline__ void attn_one(
    short8 qa0, short8 qa1, short8 kb0, short8 kb1,
    const float* v, float* o, int lr)
{
    f32x4 s = (f32x4){0.f, 0.f, 0.f, 0.f};
    s = __builtin_amdgcn_mfma_f32_16x16x32_bf16(qa0, kb0, s, 0, 0, 0);
    s = __builtin_amdgcn_mfma_f32_16x16x32_bf16(qa1, kb1, s, 0, 0, 0);
    float pp[4];
    #pragma unroll
    for (int rg = 0; rg < 4; ++rg) {
        float x = (lr < 12) ? s[rg] * 0.125f : -1e30f;
        float m = x;
        m = fmaxf(m, __shfl_xor(m, 1));
        m = fmaxf(m, __shfl_xor(m, 2));
        m = fmaxf(m, __shfl_xor(m, 4));
        m = fmaxf(m, __shfl_xor(m, 8));
        float e = (lr < 12) ? __expf(x - m) : 0.f;
        float ss = e;
        ss += __shfl_xor(ss, 1);
        ss += __shfl_xor(ss, 2);
        ss += __shfl_xor(ss, 4);
        ss += __shfl_xor(ss, 8);
        pp[rg] = e / ss;
    }
    // PV: o[h] += readlane(pp[h&3], (h>>2)*16+g) * v[g]  (SGPR broadcast)
    #pragma unroll
    for (int g = 0; g < 12; ++g) {
        #pragma unroll
        for (int h = 0; h < 12; ++h) {
            union { float f; int i; } cb;
            cb.i = __builtin_amdgcn_readlane(
                __builtin_bit_cast(int, pp[h & 3]), (h >> 2) * 16 + g);
            o[h] = fmaf(cb.f, v[g], o[h]);
        }
    }
}

__global__ __launch_bounds__(256) void headattn2(
    const u16* __restrict__ qkv1, const u16* __restrict__ qkv2,
    u16* __restrict__ sum)
{
    const int t = threadIdx.x, wv = t >> 6, l = t & 63;
    const int p = blockIdx.x * 4 + wv;
    const u16* r1 = qkv1 + (size_t)p * NQKV;
    const u16* r2 = qkv2 + (size_t)p * NQKV;
    const int lr = l & 15;
    const int fo = lr * 64 + (l >> 4) * 8;          // frag offset

    // Q/K fragments + V columns, all direct from global, issued up front
    short8 qa0_1 = *(const short8*)(r1 + fo);
    short8 qa1_1 = *(const short8*)(r1 + fo + 32);
    short8 kb0_1 = *(const short8*)(r1 + 768 + fo);
    short8 kb1_1 = *(const short8*)(r1 + 768 + fo + 32);
    short8 qa0_2 = *(const short8*)(r2 + fo);
    short8 qa1_2 = *(const short8*)(r2 + fo + 32);
    short8 kb0_2 = *(const short8*)(r2 + 768 + fo);
    short8 kb1_2 = *(const short8*)(r2 + 768 + fo + 32);
    float v1[12], v2[12];
    #pragma unroll
    for (int g = 0; g < 12; ++g) {
        v1[g] = b2f(r1[1536 + g * 64 + l]);   // 128B coalesced per g
        v2[g] = b2f(r2[1536 + g * 64 + l]);
    }

    float o[12];
    #pragma unroll
    for (int h = 0; h < 12; ++h) o[h] = 0.f;

    attn_one(qa0_1, qa1_1, kb0_1, kb1_1, v1, o, lr);
    attn_one(qa0_2, qa1_2, kb0_2, kb1_2, v2, o, lr);

    u16* orow = sum + (size_t)p * DIMC;
    #pragma unroll
    for (int h = 0; h < 12; ++h)
        orow[h * 64 + l] = f2b(o[h]);         // 128B coalesced per h
}

extern "C" void kernel_launch(void* const* d_in, const int* in_sizes, int n_in,
                              void* d_out, int out_size, void* d_ws, size_t ws_size,
                              hipStream_t stream) {
    const float* x  = (const float*)d_in[0];
    const float* wh = (const float*)d_in[1];
    const float* bh = (const float*)d_in[2];
    const float* ww = (const float*)d_in[3];
    const float* bw = (const float*)d_in[4];
    const float* wp = (const float*)d_in[5];
    const float* bp = (const float*)d_in[6];
    float* out = (float*)d_out;

    // ws (u16 elems): xb 25165824 (reused as sumb after 2nd GEMM) |
    //   whT 1769472 | wwT 1769472 | wpT 589824 | qkv1 75497472 |
    //   qkv2 75497472  => ~361 MB
    u16* xb   = (u16*)d_ws;
    u16* sumb = xb;                      // aliases xb (dead after 2nd GEMM)
    u16* whT  = xb   + 25165824;
    u16* wwT  = whT  + 1769472;
    u16* wpT  = wwT  + 1769472;
    u16* qkv1 = wpT  + 589824;
    u16* qkv2 = qkv1 + 75497472;

    cvt_bf16<<<24576, 256, 0, stream>>>(x, xb, 6291456);
    dim3 wg(36, 12, 3);
    cvt_wT<<<wg, 256, 0, stream>>>(wh, ww, wp, whT, wwT, wpT);

    dim3 gq(NQKV / 256, NPOS / 256);      // (9, 128)  -> 1152 blocks
    dim3 gp(DIMC / 256, NPOS / 256);      // (3, 128)  ->  384 blocks

    gemm256<<<gq, 512, 0, stream>>>(xb, whT, bh, qkv1, NQKV, 0);
    gemm256<<<gq, 512, 0, stream>>>(xb, wwT, bw, qkv2, NQKV, 0);
    headattn2<<<NPOS / 4, 256, 0, stream>>>(qkv1, qkv2, sumb);
    gemm256<<<gp, 512, 0, stream>>>(sumb, wpT, bp, out, DIMC, 1);
}